// Round 4
// baseline (435.096 us; speedup 1.0000x reference)
//
#include <hip/hip_runtime.h>
#include <hip/hip_bf16.h>
#include <stdint.h>

typedef short short8 __attribute__((ext_vector_type(8)));
typedef float f32x4 __attribute__((ext_vector_type(4)));

#define KKTOT 2304   // 9*256
#define PXS   40     // padded LDS row stride (elements) — kills bank-conflict cycle

__device__ __forceinline__ short f2bf(float f) {
    __hip_bfloat16 h = __float2bfloat16(f);
    return __builtin_bit_cast(short, h);
}

// ---- prep 1: demod(b,co) = 1/sqrt( sum_ci style^2 * sum_p k^2 + eps ) ------
__global__ void prep_demod(const float* __restrict__ style,
                           const float* __restrict__ kern,
                           float* __restrict__ demod)
{
    const int b = blockIdx.x, co = threadIdx.x;
    float acc = 0.f;
    for (int ci = 0; ci < 256; ++ci) {
        float s = style[b * 256 + ci];
        float k2 = 0.f;
#pragma unroll
        for (int p = 0; p < 9; ++p) {
            float w = kern[(p * 256 + ci) * 256 + co];
            k2 += w * w;
        }
        acc += s * s * k2;
    }
    demod[b * 256 + co] = 1.0f / sqrtf(acc + 1e-7f);
}

// ---- prep 2: kT(co, kidx) = bf16(kernel[kidx][co])  (transpose + downcast) -
__global__ void prep_kt(const float* __restrict__ kern,
                        __hip_bfloat16* __restrict__ kT)
{
    __shared__ float tile[64][65];
    const int t   = threadIdx.x;
    const int k0  = blockIdx.x << 6;   // 36 tiles over kidx
    const int c0  = blockIdx.y << 6;   // 4 tiles over cout
    const int col = t & 63;
    const int rb  = (t >> 6) << 4;
#pragma unroll
    for (int r = 0; r < 16; ++r) {
        int kl = rb + r;
        tile[kl][col] = kern[(size_t)(k0 + kl) * 256 + c0 + col];
    }
    __syncthreads();
#pragma unroll
    for (int r = 0; r < 16; ++r) {
        int co = rb + r;
        kT[(size_t)(c0 + co) * KKTOT + k0 + col] = __float2bfloat16(tile[col][co]);
    }
}

// ---- main: implicit-GEMM conv, f32 in / f32 out, bf16 MFMA core ------------
// One block = one (b,h) row (M=128 pixels) x 128 couts. 24 K-slices
// (dh in {-1,0,1} x 8 cin-chunks of 32). x row staged unshifted (f32->bf16,
// style folded in) into a 130-row haloed buffer (rows 0/129 zero); dw shift
// applied at ds_read; demod applied in f32 epilogue.
__global__ __launch_bounds__(256) void conv_mfma(
    const float* __restrict__ x,
    const __hip_bfloat16* __restrict__ kt,
    const float* __restrict__ style,
    const float* __restrict__ demod,
    float* __restrict__ out)
{
    __shared__ __align__(16) __hip_bfloat16 Xs[130 * PXS];       // 10.4 KB
    __shared__ __align__(16) __hip_bfloat16 Bs[3 * 128 * PXS];   // 30.7 KB
    __shared__ float Ss[256];
    __shared__ float Ds[128];

    const int t    = threadIdx.x;
    const int n0   = blockIdx.x << 7;           // cout tile: 0 or 128
    const int bh   = blockIdx.y;                // 0..1023
    const int b    = bh >> 7, h = bh & 127;
    const int wave = t >> 6, lane = t & 63;
    const int wr   = (wave >> 1) << 6;          // wave row base
    const int wc   = (wave & 1) << 6;           // wave col base
    const int l15  = lane & 15, lk = lane >> 4;
    const int mA   = t >> 2;                    // staging row 0..63
    const int koff = (t & 3) << 3;              // staging k offset (8 elems)

    if (t < 128) {
        ((float2*)Ss)[t] = ((const float2*)(style + b * 256))[t];
        Ds[t] = demod[b * 256 + n0 + t];
    }
    if (t < 32) {                               // halo rows, never re-written
        Xs[t]             = __float2bfloat16(0.f);
        Xs[129 * PXS + t] = __float2bfloat16(0.f);
    }

    f32x4 acc[4][4] = {};

    for (int sl = 0; sl < 24; ++sl) {
        const int h2 = h + (sl >> 3) - 1;       // block-uniform
        if ((unsigned)h2 >= 128u) continue;
        const int ci0     = (sl & 7) << 5;
        const int posbase = (sl >> 3) * 3;

        __syncthreads();                        // prior readers done

        // ---- stage A: x row (f32), modulate by style, downcast to bf16 ----
        const size_t rowbase = (size_t)(b * 128 + h2) * 128;
        const float* ga = x + (rowbase + mA)      * 256 + ci0 + koff;
        const float* gb = x + (rowbase + mA + 64) * 256 + ci0 + koff;
        float4 xa0 = *(const float4*)ga,       xa1 = *(const float4*)(ga + 4);
        float4 xb0 = *(const float4*)gb,       xb1 = *(const float4*)(gb + 4);
        float4 s0  = *(const float4*)&Ss[ci0 + koff];
        float4 s1  = *(const float4*)&Ss[ci0 + koff + 4];
        short8 ma, mb;
#pragma unroll
        for (int jj = 0; jj < 4; ++jj) {
            ma[jj]     = f2bf((&xa0.x)[jj] * (&s0.x)[jj]);
            ma[jj + 4] = f2bf((&xa1.x)[jj] * (&s1.x)[jj]);
            mb[jj]     = f2bf((&xb0.x)[jj] * (&s0.x)[jj]);
            mb[jj + 4] = f2bf((&xb1.x)[jj] * (&s1.x)[jj]);
        }
        *(short8*)&Xs[(mA + 1)  * PXS + koff] = ma;
        *(short8*)&Xs[(mA + 65) * PXS + koff] = mb;

        // ---- stage B: transposed bf16 kernel, 3 taps ----
        const __hip_bfloat16* gw =
            kt + (size_t)(n0 + mA) * KKTOT + posbase * 256 + ci0 + koff;
#pragma unroll
        for (int tp = 0; tp < 3; ++tp) {
            short8 w0 = *(const short8*)(gw + tp * 256);
            short8 w1 = *(const short8*)(gw + tp * 256 + 64 * KKTOT);
            *(short8*)&Bs[tp * (128 * PXS) + mA * PXS + koff]        = w0;
            *(short8*)&Bs[tp * (128 * PXS) + (mA + 64) * PXS + koff] = w1;
        }
        __syncthreads();

        // ---- MFMA: 3 taps x 4x4 tiles ----
#pragma unroll
        for (int tp = 0; tp < 3; ++tp) {        // dw=tp-1; pixel m reads Xs row m+tp
            short8 af[4], bfr[4];
#pragma unroll
            for (int i = 0; i < 4; ++i)
                af[i] = *(const short8*)&Xs[(wr + i * 16 + l15 + tp) * PXS + lk * 8];
#pragma unroll
            for (int j = 0; j < 4; ++j)
                bfr[j] = *(const short8*)&Bs[tp * (128 * PXS) + (wc + j * 16 + l15) * PXS + lk * 8];
#pragma unroll
            for (int i = 0; i < 4; ++i)
#pragma unroll
                for (int j = 0; j < 4; ++j)
                    acc[i][j] = __builtin_amdgcn_mfma_f32_16x16x32_bf16(
                        af[i], bfr[j], acc[i][j], 0, 0, 0);
        }
    }

    // ---- epilogue: demod scale + f32 store (C/D: col=lane&15, row=(lane>>4)*4+r)
    float dj[4];
#pragma unroll
    for (int j = 0; j < 4; ++j) dj[j] = Ds[wc + j * 16 + l15];
    const size_t obase = (size_t)(b * 128 + h) * 128 * 256 + n0;
#pragma unroll
    for (int i = 0; i < 4; ++i) {
#pragma unroll
        for (int j = 0; j < 4; ++j) {
            const int n = wc + j * 16 + l15;
#pragma unroll
            for (int r = 0; r < 4; ++r) {
                const int m = wr + i * 16 + lk * 4 + r;
                out[obase + (size_t)m * 256 + n] = acc[i][j][r] * dj[j];
            }
        }
    }
}

extern "C" void kernel_launch(void* const* d_in, const int* in_sizes, int n_in,
                              void* d_out, int out_size, void* d_ws, size_t ws_size,
                              hipStream_t stream)
{
    const float* x     = (const float*)d_in[0];
    const float* style = (const float*)d_in[1];
    const float* kern  = (const float*)d_in[2];
    float* out = (float*)d_out;

    char*  ws    = (char*)d_ws;
    float* demod = (float*)ws;                          // 2048 f32 (8 KB)
    __hip_bfloat16* kT = (__hip_bfloat16*)(ws + 8192);  // 589824 bf16 (1.18 MB)

    prep_demod<<<8, 256, 0, stream>>>(style, kern, demod);
    prep_kt   <<<dim3(36, 4), 256, 0, stream>>>(kern, kT);
    conv_mfma <<<dim3(2, 1024), 256, 0, stream>>>(x, kT, style, demod, out);
}

// Round 5
// 361.866 us; speedup vs baseline: 1.2024x; 1.2024x over previous
//
#include <hip/hip_runtime.h>
#include <hip/hip_bf16.h>
#include <stdint.h>

typedef short short8 __attribute__((ext_vector_type(8)));
typedef float f32x4 __attribute__((ext_vector_type(4)));

#define KKTOT 2304   // 9*256
#define PXS   40     // padded LDS row stride (elements) — fragment reads 2-way max

__device__ __forceinline__ short f2bf(float f) {
    __hip_bfloat16 h = __float2bfloat16(f);
    return __builtin_bit_cast(short, h);
}

// ---- prep 1a: K2(ci,co) = sum_p kernel[p,ci,co]^2  (256 blocks) ------------
__global__ void prep_k2(const float* __restrict__ kern, float* __restrict__ K2)
{
    const int ci = blockIdx.x, co = threadIdx.x;
    float acc = 0.f;
#pragma unroll
    for (int p = 0; p < 9; ++p) {
        float w = kern[(p * 256 + ci) * 256 + co];
        acc += w * w;
    }
    K2[ci * 256 + co] = acc;
}

// ---- prep 1b: demod(b,co) = 1/sqrt( sum_ci style^2 * K2 + eps ) ------------
__global__ void prep_demod(const float* __restrict__ style,
                           const float* __restrict__ K2,
                           float* __restrict__ demod)
{
    const int b = blockIdx.x, co = threadIdx.x;
    __shared__ float s2[256];
    float s = style[b * 256 + co];
    s2[co] = s * s;
    __syncthreads();
    float acc = 0.f;
#pragma unroll 8
    for (int ci = 0; ci < 256; ++ci)
        acc += s2[ci] * K2[ci * 256 + co];
    demod[b * 256 + co] = 1.0f / sqrtf(acc + 1e-7f);
}

// ---- prep 2: kT(co, kidx) = bf16(kernel[kidx][co])  (transpose + downcast) -
__global__ void prep_kt(const float* __restrict__ kern,
                        __hip_bfloat16* __restrict__ kT)
{
    __shared__ float tile[64][65];
    const int t   = threadIdx.x;
    const int k0  = blockIdx.x << 6;   // 36 tiles over kidx
    const int c0  = blockIdx.y << 6;   // 4 tiles over cout
    const int col = t & 63;
    const int rb  = (t >> 6) << 4;
#pragma unroll
    for (int r = 0; r < 16; ++r) {
        int kl = rb + r;
        tile[kl][col] = kern[(size_t)(k0 + kl) * 256 + c0 + col];
    }
    __syncthreads();
#pragma unroll
    for (int r = 0; r < 16; ++r) {
        int co = rb + r;
        kT[(size_t)(c0 + co) * KKTOT + k0 + col] = __float2bfloat16(tile[col][co]);
    }
}

// ---- main: implicit-GEMM conv, f32 in / f32 out, bf16 MFMA core ------------
// One block = one (b,h) row (M=128 pixels) x 128 couts. 24 K-slices
// (dh in {-1,0,1} x 8 cin-chunks of 32). x row staged unshifted (f32->bf16,
// style folded in) into a 130-row haloed buffer (rows 0/129 zero); dw shift
// applied at ds_read; demod applied in f32 epilogue.
// Flat grid + XCD swizzle: HW round-robins blockIdx.x across 8 XCDs, so
// L = (bid&7)*256 + (bid>>3) gives each XCD a contiguous (n0,bh) range —
// blocks sharing x rows share a per-XCD L2.
__global__ __launch_bounds__(256) void conv_mfma(
    const float* __restrict__ x,
    const __hip_bfloat16* __restrict__ kt,
    const float* __restrict__ style,
    const float* __restrict__ demod,
    float* __restrict__ out)
{
    __shared__ __align__(16) __hip_bfloat16 Xs[130 * PXS];       // 10.4 KB
    __shared__ __align__(16) __hip_bfloat16 Bs[3 * 128 * PXS];   // 30.7 KB
    __shared__ float Ss[256];
    __shared__ float Ds[128];

    const int t    = threadIdx.x;
    const int bid  = blockIdx.x;
    const int L    = ((bid & 7) << 8) | (bid >> 3);   // XCD-contiguous work id
    const int n0   = (L & 1) << 7;                    // cout tile: 0 or 128
    const int bh   = L >> 1;                          // 0..1023
    const int b    = bh >> 7, h = bh & 127;
    const int wave = t >> 6, lane = t & 63;
    const int wr   = (wave >> 1) << 6;          // wave row base
    const int wc   = (wave & 1) << 6;           // wave col base
    const int l15  = lane & 15, lk = lane >> 4;
    const int mA   = t >> 2;                    // staging row 0..63
    const int koff = (t & 3) << 3;              // staging k offset (8 elems)

    if (t < 128) {
        ((float2*)Ss)[t] = ((const float2*)(style + b * 256))[t];
        Ds[t] = demod[b * 256 + n0 + t];
    }
    if (t < 32) {                               // halo rows, never re-written
        Xs[t]             = __float2bfloat16(0.f);
        Xs[129 * PXS + t] = __float2bfloat16(0.f);
    }

    f32x4 acc[4][4] = {};

    for (int sl = 0; sl < 24; ++sl) {
        const int h2 = h + (sl >> 3) - 1;       // block-uniform
        if ((unsigned)h2 >= 128u) continue;
        const int ci0     = (sl & 7) << 5;
        const int posbase = (sl >> 3) * 3;

        __syncthreads();                        // prior readers done

        // ---- stage A: x row (f32), modulate by style, downcast to bf16 ----
        const size_t rowbase = (size_t)(b * 128 + h2) * 128;
        const float* ga = x + (rowbase + mA)      * 256 + ci0 + koff;
        const float* gb = x + (rowbase + mA + 64) * 256 + ci0 + koff;
        float4 xa0 = *(const float4*)ga,       xa1 = *(const float4*)(ga + 4);
        float4 xb0 = *(const float4*)gb,       xb1 = *(const float4*)(gb + 4);
        float4 s0  = *(const float4*)&Ss[ci0 + koff];
        float4 s1  = *(const float4*)&Ss[ci0 + koff + 4];
        short8 ma, mb;
#pragma unroll
        for (int jj = 0; jj < 4; ++jj) {
            ma[jj]     = f2bf((&xa0.x)[jj] * (&s0.x)[jj]);
            ma[jj + 4] = f2bf((&xa1.x)[jj] * (&s1.x)[jj]);
            mb[jj]     = f2bf((&xb0.x)[jj] * (&s0.x)[jj]);
            mb[jj + 4] = f2bf((&xb1.x)[jj] * (&s1.x)[jj]);
        }
        *(short8*)&Xs[(mA + 1)  * PXS + koff] = ma;
        *(short8*)&Xs[(mA + 65) * PXS + koff] = mb;

        // ---- stage B: transposed bf16 kernel, 3 taps ----
        const __hip_bfloat16* gw =
            kt + (size_t)(n0 + mA) * KKTOT + posbase * 256 + ci0 + koff;
#pragma unroll
        for (int tp = 0; tp < 3; ++tp) {
            short8 w0 = *(const short8*)(gw + tp * 256);
            short8 w1 = *(const short8*)(gw + tp * 256 + 64 * KKTOT);
            *(short8*)&Bs[tp * (128 * PXS) + mA * PXS + koff]        = w0;
            *(short8*)&Bs[tp * (128 * PXS) + (mA + 64) * PXS + koff] = w1;
        }
        __syncthreads();

        // ---- MFMA: 3 taps x 4x4 tiles ----
#pragma unroll
        for (int tp = 0; tp < 3; ++tp) {        // dw=tp-1; pixel m reads Xs row m+tp
            short8 af[4], bfr[4];
#pragma unroll
            for (int i = 0; i < 4; ++i)
                af[i] = *(const short8*)&Xs[(wr + i * 16 + l15 + tp) * PXS + lk * 8];
#pragma unroll
            for (int j = 0; j < 4; ++j)
                bfr[j] = *(const short8*)&Bs[tp * (128 * PXS) + (wc + j * 16 + l15) * PXS + lk * 8];
#pragma unroll
            for (int i = 0; i < 4; ++i)
#pragma unroll
                for (int j = 0; j < 4; ++j)
                    acc[i][j] = __builtin_amdgcn_mfma_f32_16x16x32_bf16(
                        af[i], bfr[j], acc[i][j], 0, 0, 0);
        }
    }

    // ---- epilogue: demod scale + f32 store (C/D: col=lane&15, row=(lane>>4)*4+r)
    float dj[4];
#pragma unroll
    for (int j = 0; j < 4; ++j) dj[j] = Ds[wc + j * 16 + l15];
    const size_t obase = (size_t)(b * 128 + h) * 128 * 256 + n0;
#pragma unroll
    for (int i = 0; i < 4; ++i) {
#pragma unroll
        for (int j = 0; j < 4; ++j) {
            const int n = wc + j * 16 + l15;
#pragma unroll
            for (int r = 0; r < 4; ++r) {
                const int m = wr + i * 16 + lk * 4 + r;
                out[obase + (size_t)m * 256 + n] = acc[i][j][r] * dj[j];
            }
        }
    }
}

extern "C" void kernel_launch(void* const* d_in, const int* in_sizes, int n_in,
                              void* d_out, int out_size, void* d_ws, size_t ws_size,
                              hipStream_t stream)
{
    const float* x     = (const float*)d_in[0];
    const float* style = (const float*)d_in[1];
    const float* kern  = (const float*)d_in[2];
    float* out = (float*)d_out;

    char*  ws    = (char*)d_ws;
    float* demod = (float*)ws;                          // 2048 f32   (8 KB)
    float* K2    = (float*)(ws + 8192);                 // 65536 f32  (256 KB)
    __hip_bfloat16* kT = (__hip_bfloat16*)(ws + 270336); // 589824 bf16 (1.18 MB)

    prep_k2   <<<256, 256, 0, stream>>>(kern, K2);
    prep_demod<<<8,   256, 0, stream>>>(style, K2, demod);
    prep_kt   <<<dim3(36, 4), 256, 0, stream>>>(kern, kT);
    conv_mfma <<<2048, 256, 0, stream>>>(x, kT, style, demod, out);
}